// Round 2
// baseline (22382.445 us; speedup 1.0000x reference)
//
#include <hip/hip_runtime.h>

#define Bn 64
#define Cn 128
#define Hn 36
#define Wn 100
#define KSn 9

// element strides in the [b][c][axis0][axis1] buffers
#define B_STRIDE (Cn * Hn * Wn)  // 460800
#define C_STRIDE (Hn * Wn)       // 3600

// ---------------- copy x -> buf ----------------
__global__ void __launch_bounds__(256) k_copy(const float4* __restrict__ s,
                                              float4* __restrict__ d, int n4) {
  int i = blockIdx.x * 256 + threadIdx.x;
  if (i < n4) d[i] = s[i];
}

// ---------------- generic scan step ----------------
// One lane = one flat output index n over (b, inner); 8 co per block (blockIdx.y).
// buf[b][co][sc][inner] += relu( sum_{ci,k} buf[b][ci][sp][inner+k-4] * wt[co][ci][k] )
// Addressing: elem = b*B_STRIDE + c*C_STRIDE + scanpos*SS + inner*IS.
//   H-step           : NINNER=100 (inner=w), IS=1,   SS=100  (layout [b][c][h][w])
//   W-step transposed: NINNER=36  (inner=h), IS=1,   SS=36   (layout [b][c][w][h])
//   W-step direct    : NINNER=36  (inner=h), IS=100, SS=1    (layout [b][c][h][w])
// No LDS: window loads hit L1/L2 (uniform s_base per ci + per-lane voffset);
// edges handled by clamp + cndmask (zero padding semantics).
template <int NINNER, int IS, int SS>
__global__ void __launch_bounds__(64) k_step(float* __restrict__ buf,
                                             const float* __restrict__ wt,
                                             int sp, int sc) {
  const int lane = threadIdx.x;                 // 0..63
  const int n = blockIdx.x * 64 + lane;         // flat over (b, inner)
  const int cog = blockIdx.y;                   // co group of 8 (wave-uniform)
  const int b = n / NINNER;
  const int inner = n - b * NINNER;

  // per-lane tap offsets (elements), clamped; validity masks (loop-invariant)
  const int base = b * B_STRIDE + sp * SS;
  int offk[KSn];
  bool ok[KSn];
#pragma unroll
  for (int k = 0; k < KSn; ++k) {
    int p = inner + k - 4;
    ok[k] = (p >= 0) && (p < NINNER);
    int pc = p < 0 ? 0 : (p >= NINNER ? NINNER - 1 : p);
    offk[k] = base + pc * IS;
  }

  float acc[8] = {0.f, 0.f, 0.f, 0.f, 0.f, 0.f, 0.f, 0.f};
  const float* wb = wt + (size_t)cog * 8 * Cn * KSn;

#pragma unroll 2
  for (int ci = 0; ci < Cn; ++ci) {
    const float* cb = buf + ci * C_STRIDE;      // uniform base -> s[base]+voff loads
    float p[KSn];
#pragma unroll
    for (int k = 0; k < KSn; ++k) {
      float v = cb[offk[k]];                    // speculative (clamped, in-bounds)
      p[k] = ok[k] ? v : 0.f;                   // v_cndmask
    }
    const float* wr = wb + ci * KSn;
#pragma unroll
    for (int j = 0; j < 8; ++j) {
      const float* w9 = wr + j * Cn * KSn;      // wave-uniform -> s_load
#pragma unroll
      for (int k = 0; k < KSn; ++k) acc[j] = fmaf(p[k], w9[k], acc[j]);
    }
  }

  float* ob = buf + b * B_STRIDE + (cog * 8) * C_STRIDE + sc * SS + inner * IS;
#pragma unroll
  for (int j = 0; j < 8; ++j) ob[j * C_STRIDE] += fmaxf(acc[j], 0.f);
}

// ---------------- transpose [b][c][h][w] -> [b][c][w][h] ----------------
__global__ void __launch_bounds__(256) k_t_hw2wh(const float* __restrict__ in,
                                                 float* __restrict__ out) {
  __shared__ float tile[Hn][Wn + 1];
  const int bc = blockIdx.x;
  const float* ib = in + (size_t)bc * C_STRIDE;
  float* ob = out + (size_t)bc * C_STRIDE;
  for (int f = threadIdx.x; f < Hn * Wn; f += 256) tile[f / Wn][f % Wn] = ib[f];
  __syncthreads();
  for (int f = threadIdx.x; f < Hn * Wn; f += 256) {
    int w = f / Hn, h = f % Hn;
    ob[f] = tile[h][w];
  }
}

// ---------------- transpose back [b][c][w][h] -> [b][c][h][w] ----------------
__global__ void __launch_bounds__(256) k_t_wh2hw(const float* __restrict__ in,
                                                 float* __restrict__ out) {
  __shared__ float tile[Hn][Wn + 1];
  const int bc = blockIdx.x;
  const float* ib = in + (size_t)bc * C_STRIDE;
  float* ob = out + (size_t)bc * C_STRIDE;
  for (int f = threadIdx.x; f < Hn * Wn; f += 256) {
    int w = f / Hn, h = f % Hn;
    tile[h][w] = ib[f];
  }
  __syncthreads();
  for (int f = threadIdx.x; f < Hn * Wn; f += 256) ob[f] = tile[f / Wn][f % Wn];
}

extern "C" void kernel_launch(void* const* d_in, const int* in_sizes, int n_in,
                              void* d_out, int out_size, void* d_ws, size_t ws_size,
                              hipStream_t stream) {
  const float* x  = (const float*)d_in[0];
  const float* wd = (const float*)d_in[1];
  const float* wu = (const float*)d_in[2];
  const float* wr = (const float*)d_in[3];
  const float* wl = (const float*)d_in[4];
  float* buf = (float*)d_out;
  const size_t nelem = (size_t)Bn * B_STRIDE;  // 29,491,200

  k_copy<<<(int)(nelem / 4 + 255) / 256, 256, 0, stream>>>(
      (const float4*)x, (float4*)buf, (int)(nelem / 4));

  // ---- H phase: grid.x = 64*100/64 = 100 flat-n blocks, 16 co-groups ----
  dim3 gh(Bn * Wn / 64, Cn / 8);
  for (int hh = 1; hh < Hn; ++hh)      // down
    k_step<Wn, 1, Wn><<<gh, 64, 0, stream>>>(buf, wd, hh - 1, hh);
  for (int hh = Hn - 2; hh >= 0; --hh) // up
    k_step<Wn, 1, Wn><<<gh, 64, 0, stream>>>(buf, wu, hh + 1, hh);

  // ---- W phase ----
  dim3 gw(Bn * Hn / 64, Cn / 8);       // 36 x 16
  const bool use_t = (ws_size >= nelem * sizeof(float));
  if (use_t) {
    float* tb = (float*)d_ws;          // transposed [b][c][w][h]
    k_t_hw2wh<<<Bn * Cn, 256, 0, stream>>>(buf, tb);
    for (int ww = 1; ww < Wn; ++ww)      // right
      k_step<Hn, 1, Hn><<<gw, 64, 0, stream>>>(tb, wr, ww - 1, ww);
    for (int ww = Wn - 2; ww >= 0; --ww) // left
      k_step<Hn, 1, Hn><<<gw, 64, 0, stream>>>(tb, wl, ww + 1, ww);
    k_t_wh2hw<<<Bn * Cn, 256, 0, stream>>>(tb, buf);
  } else {
    // direct (strided) fallback on [b][c][h][w]
    for (int ww = 1; ww < Wn; ++ww)
      k_step<Hn, Wn, 1><<<gw, 64, 0, stream>>>(buf, wr, ww - 1, ww);
    for (int ww = Wn - 2; ww >= 0; --ww)
      k_step<Hn, Wn, 1><<<gw, 64, 0, stream>>>(buf, wl, ww + 1, ww);
  }
}

// Round 3
// 10196.603 us; speedup vs baseline: 2.1951x; 2.1951x over previous
//
#include <hip/hip_runtime.h>

#define Bn 64
#define Cn 128
#define Hn 36
#define Wn 100
#define KSn 9

#define B_STRIDE (Cn * Hn * Wn)  // 460800
#define C_STRIDE (Hn * Wn)       // 3600

// prepped weight strides (floats per (cogroup, ci) chunk)
#define WH_CHUNK 80  // 8 co * 9 taps = 72 used, pad 8
#define WW_CHUNK 40  // 4 co * 9 taps = 36 used, pad 4
#define WH_SIZE (16 * Cn * WH_CHUNK)  // 163840 floats
#define WW_SIZE (32 * Cn * WW_CHUNK)  // 163840 floats

// ---------------- copy x -> buf ----------------
__global__ void __launch_bounds__(256) k_copy(const float4* __restrict__ s,
                                              float4* __restrict__ d, int n4) {
  int i = blockIdx.x * 256 + threadIdx.x;
  if (i < n4) d[i] = s[i];
}

// ---------------- weight prep: [co][ci][k] -> [cog][ci][j*9+k] contiguous ----
__global__ void __launch_bounds__(256) k_prep_h(const float* __restrict__ w,
                                                float* __restrict__ o) {
  int i = blockIdx.x * 256 + threadIdx.x;
  if (i >= 16 * Cn * 72) return;
  int k = i % 9, j = (i / 9) % 8, ci = (i / 72) % Cn, cog = i / (72 * Cn);
  o[(cog * Cn + ci) * WH_CHUNK + j * 9 + k] = w[((cog * 8 + j) * Cn + ci) * KSn + k];
}
__global__ void __launch_bounds__(256) k_prep_w(const float* __restrict__ w,
                                                float* __restrict__ o) {
  int i = blockIdx.x * 256 + threadIdx.x;
  if (i >= 32 * Cn * 36) return;
  int k = i % 9, j = (i / 9) % 4, ci = (i / 36) % Cn, coq = i / (36 * Cn);
  o[(coq * Cn + ci) * WW_CHUNK + j * 9 + k] = w[((coq * 4 + j) * Cn + ci) * KSn + k];
}

// ---------------- H-direction step (fast) ----------------
// grid (Bn, Cn/16), block 256 (4 waves). 2 co-groups of 8 share one staging.
__global__ void __launch_bounds__(256) k_hstep2(float* __restrict__ buf,
                                                const float* __restrict__ wp,
                                                int hp, int hc) {
  __shared__ float prev[Cn][Wn + 8];  // 55.3 KB -> 2 blocks/CU
  const int b = blockIdx.x;
  const int t = threadIdx.x;

  const float* rb = buf + ((size_t)b * Cn * Hn + hp) * Wn;
  for (int g = t; g < Cn * (Wn / 4); g += 256) {
    int ci = g / 25, wq = g % 25;
    float4 v = *(const float4*)(rb + (size_t)ci * C_STRIDE + wq * 4);
    *(float4*)&prev[ci][4 + wq * 4] = v;
  }
  for (int g = t; g < Cn * 8; g += 256) {
    int ci = g >> 3, s = g & 7;
    prev[ci][(s < 4) ? s : (Wn + s)] = 0.f;
  }
  __syncthreads();

  const int w = t & 127;
  if (w >= Wn) return;
  const int cog = blockIdx.y * 2 + __builtin_amdgcn_readfirstlane(t >> 7);

  float acc[8] = {0.f, 0.f, 0.f, 0.f, 0.f, 0.f, 0.f, 0.f};
  const float* wb = wp + (size_t)cog * Cn * WH_CHUNK;  // scalar base
#pragma unroll 2
  for (int ci = 0; ci < Cn; ++ci) {
    float p[KSn];
#pragma unroll
    for (int k = 0; k < KSn; ++k) p[k] = prev[ci][w + k];
    const float* wr = wb + ci * WH_CHUNK;  // contiguous 72 dwords -> s_load_dwordx16
#pragma unroll
    for (int j = 0; j < 8; ++j)
#pragma unroll
      for (int k = 0; k < KSn; ++k) acc[j] = fmaf(p[k], wr[j * 9 + k], acc[j]);
  }
  float* ob = buf + ((size_t)(b * Cn + cog * 8) * Hn + hc) * Wn + w;
#pragma unroll
  for (int j = 0; j < 8; ++j) ob[(size_t)j * C_STRIDE] += fmaxf(acc[j], 0.f);
}

// ---------------- W-direction step (fast, transposed layout [b][c][w][h]) ----
// grid (Bn, Cn/16), block 256 (4 waves; wave v -> co-quad). 22.5 KB LDS.
__global__ void __launch_bounds__(256) k_wstep2(float* __restrict__ tb,
                                                const float* __restrict__ wp,
                                                int wpos, int wc) {
  __shared__ float prev[Cn][Hn + 8];
  const int b = blockIdx.x;
  const int t = threadIdx.x;

  const float* cb = tb + ((size_t)b * Cn * Wn + wpos) * Hn;
  for (int g = t; g < Cn * (Hn / 4); g += 256) {
    int ci = g / 9, hq = g % 9;
    float4 v = *(const float4*)(cb + (size_t)ci * C_STRIDE + hq * 4);
    *(float4*)&prev[ci][4 + hq * 4] = v;
  }
  for (int g = t; g < Cn * 8; g += 256) {
    int ci = g >> 3, s = g & 7;
    prev[ci][(s < 4) ? s : (Hn + s)] = 0.f;
  }
  __syncthreads();

  const int h = t & 63;
  if (h >= Hn) return;
  const int coq = blockIdx.y * 4 + __builtin_amdgcn_readfirstlane(t >> 6);

  float acc[4] = {0.f, 0.f, 0.f, 0.f};
  const float* wb = wp + (size_t)coq * Cn * WW_CHUNK;  // scalar base
#pragma unroll 2
  for (int ci = 0; ci < Cn; ++ci) {
    float p[KSn];
#pragma unroll
    for (int k = 0; k < KSn; ++k) p[k] = prev[ci][h + k];
    const float* wr = wb + ci * WW_CHUNK;  // contiguous 36 dwords
#pragma unroll
    for (int j = 0; j < 4; ++j)
#pragma unroll
      for (int k = 0; k < KSn; ++k) acc[j] = fmaf(p[k], wr[j * 9 + k], acc[j]);
  }
  float* ob = tb + ((size_t)(b * Cn + coq * 4) * Wn + wc) * Hn + h;
#pragma unroll
  for (int j = 0; j < 4; ++j) ob[(size_t)j * C_STRIDE] += fmaxf(acc[j], 0.f);
}

// ---------------- transposes ----------------
__global__ void __launch_bounds__(256) k_t_hw2wh(const float* __restrict__ in,
                                                 float* __restrict__ out) {
  __shared__ float tile[Hn][Wn + 1];
  const int bc = blockIdx.x;
  const float* ib = in + (size_t)bc * C_STRIDE;
  float* ob = out + (size_t)bc * C_STRIDE;
  for (int f = threadIdx.x; f < Hn * Wn; f += 256) tile[f / Wn][f % Wn] = ib[f];
  __syncthreads();
  for (int f = threadIdx.x; f < Hn * Wn; f += 256) {
    int w = f / Hn, h = f % Hn;
    ob[f] = tile[h][w];
  }
}
__global__ void __launch_bounds__(256) k_t_wh2hw(const float* __restrict__ in,
                                                 float* __restrict__ out) {
  __shared__ float tile[Hn][Wn + 1];
  const int bc = blockIdx.x;
  const float* ib = in + (size_t)bc * C_STRIDE;
  float* ob = out + (size_t)bc * C_STRIDE;
  for (int f = threadIdx.x; f < Hn * Wn; f += 256) {
    int w = f / Hn, h = f % Hn;
    tile[h][w] = ib[f];
  }
  __syncthreads();
  for (int f = threadIdx.x; f < Hn * Wn; f += 256) ob[f] = tile[f / Wn][f % Wn];
}

// ---------------- fallback kernels (round-1, proven) ----------------
__global__ void __launch_bounds__(128) k_hstep(float* __restrict__ buf,
                                               const float* __restrict__ wt,
                                               int hp, int hc) {
  __shared__ float prev[Cn][Wn + 8];
  const int b = blockIdx.x;
  const int cog = blockIdx.y;
  const int t = threadIdx.x;
  const float* rb = buf + ((size_t)b * Cn * Hn + hp) * Wn;
  for (int g = t; g < Cn * (Wn / 4); g += 128) {
    int ci = g / 25, wq = g % 25;
    float4 v = *(const float4*)(rb + (size_t)ci * C_STRIDE + wq * 4);
    *(float4*)&prev[ci][4 + wq * 4] = v;
  }
  for (int g = t; g < Cn * 8; g += 128) {
    int ci = g >> 3, s = g & 7;
    prev[ci][(s < 4) ? s : (Wn + s)] = 0.f;
  }
  __syncthreads();
  if (t >= Wn) return;
  float acc[8] = {0.f, 0.f, 0.f, 0.f, 0.f, 0.f, 0.f, 0.f};
  const float* wb = wt + (size_t)cog * 8 * Cn * KSn;
  for (int ci = 0; ci < Cn; ++ci) {
    float p[KSn];
#pragma unroll
    for (int k = 0; k < KSn; ++k) p[k] = prev[ci][t + k];
#pragma unroll
    for (int j = 0; j < 8; ++j) {
      const float* w9 = wb + ((size_t)j * Cn + ci) * KSn;
#pragma unroll
      for (int k = 0; k < KSn; ++k) acc[j] = fmaf(p[k], w9[k], acc[j]);
    }
  }
  float* ob = buf + ((size_t)(b * Cn + cog * 8) * Hn + hc) * Wn + t;
#pragma unroll
  for (int j = 0; j < 8; ++j) ob[(size_t)j * C_STRIDE] += fmaxf(acc[j], 0.f);
}
__global__ void __launch_bounds__(128) k_wstep_d(float* __restrict__ buf,
                                                 const float* __restrict__ wt,
                                                 int wpos, int wc) {
  __shared__ float prev[Cn][Hn + 8];
  const int b = blockIdx.x;
  const int cog = blockIdx.y;
  const int t = threadIdx.x;
  const int h = t & 63;
  const int jb = __builtin_amdgcn_readfirstlane((t >> 6) * 4);
  for (int g = t; g < Cn * Hn; g += 128) {
    int ci = g / Hn, hh = g % Hn;
    prev[ci][4 + hh] = buf[((size_t)(b * Cn + ci) * Hn + hh) * Wn + wpos];
  }
  for (int g = t; g < Cn * 8; g += 128) {
    int ci = g >> 3, s = g & 7;
    prev[ci][(s < 4) ? s : (Hn + s)] = 0.f;
  }
  __syncthreads();
  if (h >= Hn) return;
  float acc[4] = {0.f, 0.f, 0.f, 0.f};
  const float* wb = wt + (size_t)(cog * 8 + jb) * Cn * KSn;
  for (int ci = 0; ci < Cn; ++ci) {
    float p[KSn];
#pragma unroll
    for (int k = 0; k < KSn; ++k) p[k] = prev[ci][h + k];
#pragma unroll
    for (int j = 0; j < 4; ++j) {
      const float* w9 = wb + ((size_t)j * Cn + ci) * KSn;
#pragma unroll
      for (int k = 0; k < KSn; ++k) acc[j] = fmaf(p[k], w9[k], acc[j]);
    }
  }
  float* ob = buf + ((size_t)(b * Cn + cog * 8 + jb) * Hn + h) * Wn + wc;
#pragma unroll
  for (int j = 0; j < 4; ++j) ob[(size_t)j * C_STRIDE] += fmaxf(acc[j], 0.f);
}

extern "C" void kernel_launch(void* const* d_in, const int* in_sizes, int n_in,
                              void* d_out, int out_size, void* d_ws, size_t ws_size,
                              hipStream_t stream) {
  const float* x  = (const float*)d_in[0];
  const float* wd = (const float*)d_in[1];
  const float* wu = (const float*)d_in[2];
  const float* wr = (const float*)d_in[3];
  const float* wl = (const float*)d_in[4];
  float* buf = (float*)d_out;
  const size_t nelem = (size_t)Bn * B_STRIDE;  // 29,491,200 floats
  const size_t need = (nelem + 2 * (size_t)WH_SIZE + 2 * (size_t)WW_SIZE) * 4;

  k_copy<<<(int)(nelem / 4 + 255) / 256, 256, 0, stream>>>(
      (const float4*)x, (float4*)buf, (int)(nelem / 4));

  if (ws_size >= need) {
    float* tb  = (float*)d_ws;                 // transposed buffer
    float* pwd = tb + nelem;                   // prepped weights
    float* pwu = pwd + WH_SIZE;
    float* pwr = pwu + WH_SIZE;
    float* pwl = pwr + WW_SIZE;

    k_prep_h<<<(16 * Cn * 72 + 255) / 256, 256, 0, stream>>>(wd, pwd);
    k_prep_h<<<(16 * Cn * 72 + 255) / 256, 256, 0, stream>>>(wu, pwu);
    k_prep_w<<<(32 * Cn * 36 + 255) / 256, 256, 0, stream>>>(wr, pwr);
    k_prep_w<<<(32 * Cn * 36 + 255) / 256, 256, 0, stream>>>(wl, pwl);

    dim3 gh(Bn, Cn / 16);  // 64 x 8 blocks of 256
    for (int hh = 1; hh < Hn; ++hh)
      k_hstep2<<<gh, 256, 0, stream>>>(buf, pwd, hh - 1, hh);
    for (int hh = Hn - 2; hh >= 0; --hh)
      k_hstep2<<<gh, 256, 0, stream>>>(buf, pwu, hh + 1, hh);

    k_t_hw2wh<<<Bn * Cn, 256, 0, stream>>>(buf, tb);
    dim3 gw(Bn, Cn / 16);
    for (int ww = 1; ww < Wn; ++ww)
      k_wstep2<<<gw, 256, 0, stream>>>(tb, pwr, ww - 1, ww);
    for (int ww = Wn - 2; ww >= 0; --ww)
      k_wstep2<<<gw, 256, 0, stream>>>(tb, pwl, ww + 1, ww);
    k_t_wh2hw<<<Bn * Cn, 256, 0, stream>>>(tb, buf);
  } else {
    // proven round-1 fallback (raw weights, direct W)
    dim3 g8(Bn, Cn / 8);
    for (int hh = 1; hh < Hn; ++hh)
      k_hstep<<<g8, 128, 0, stream>>>(buf, wd, hh - 1, hh);
    for (int hh = Hn - 2; hh >= 0; --hh)
      k_hstep<<<g8, 128, 0, stream>>>(buf, wu, hh + 1, hh);
    for (int ww = 1; ww < Wn; ++ww)
      k_wstep_d<<<g8, 128, 0, stream>>>(buf, wr, ww - 1, ww);
    for (int ww = Wn - 2; ww >= 0; --ww)
      k_wstep_d<<<g8, 128, 0, stream>>>(buf, wl, ww + 1, ww);
  }
}